// Round 5
// baseline (134.418 us; speedup 1.0000x reference)
//
#include <hip/hip_runtime.h>

#define B_    2
#define T_    400
#define NCH_  8
#define NBIN_ 512
#define NBAND_ 40
#define NPV_  64

using short8  = __attribute__((ext_vector_type(8))) short;
using float4v = __attribute__((ext_vector_type(4))) float;

// bf16 round-to-nearest-even pack of two floats into one dword (lo=x, hi=y)
static __device__ inline unsigned pkbf(float x, float y) {
  union { float f; unsigned u; } a, b;
  a.f = x; b.f = y;
  unsigned ra = a.u + 0x7fffu + ((a.u >> 16) & 1u);
  unsigned rb = b.u + 0x7fffu + ((b.u >> 16) & 1u);
  return (ra >> 16) | (rb & 0xffff0000u);
}
// unpack bf16 pair dword -> two f32 (lo, hi)
static __device__ inline void upk(unsigned u, float& lo, float& hi) {
  union { unsigned q; float f; } a, b;
  a.q = u << 16; b.q = u & 0xffff0000u;
  lo = a.f; hi = b.f;
}

// ws layout (bytes):
//   [0..159]              : dsinv[40] floats
//   [1024, 1024+196608)   : band B-frags: F=((g*3+n)*32+s)*64+lane, uint4 each
//   [197632, 197632+16384): epi  B-frags: E=(nt*4+ks)*64+lane, uint4 each
__global__ __launch_bounds__(256) void pv_prep(
    const float* __restrict__ bmr, const float* __restrict__ bmi,
    const float* __restrict__ c2pr, const float* __restrict__ c2pi,
    float* __restrict__ ws)
{
  const int tid = threadIdx.x;
  const int blk = blockIdx.x;
  if (blk == 0) {
    __shared__ float sds[256];
    int k = tid & 63, part = tid >> 6;
    float s = 0.f;
    if (k < NBAND_) {
      const float* col = bmr + k;
      #pragma unroll 16
      for (int f = part * 128; f < part * 128 + 128; f++) s += col[f * 40];
    }
    sds[tid] = s;
    __syncthreads();
    if (tid < NBAND_) {
      float t = sds[tid] + sds[tid + 64] + sds[tid + 128] + sds[tid + 192];
      ws[tid] = 1.0f / fmaxf(t, 1e-20f);
    }
  } else if (blk <= 48) {
    int F = (blk - 1) * 256 + tid;     // 0..12287
    int l = F & 63;
    int rest = F >> 6;
    int s5 = rest & 31;
    int gn = rest >> 5;
    int n = gn % 3, g = gn / 3;
    int k = n * 16 + (l & 15);
    unsigned dw[4];
    #pragma unroll
    for (int t2 = 0; t2 < 4; t2++) {
      float v0 = 0.f, v1 = 0.f;
      if (k < NBAND_) {
        int kd = s5 * 32 + (l >> 4) * 8 + 2 * t2;
        int f = kd >> 1;
        if (g == 0) { v0 = bmr[f * 40 + k]; v1 = -bmi[f * 40 + k]; }
        else        { v0 = bmi[f * 40 + k]; v1 =  bmr[f * 40 + k]; }
      }
      dw[t2] = pkbf(v0, v1);
    }
    ((uint4*)((char*)ws + 1024))[F] = make_uint4(dw[0], dw[1], dw[2], dw[3]);
  } else {
    int F2 = (blk - 49) * 256 + tid;   // 0..1023
    int lane = F2 & 63, E = F2 >> 6;
    int nt = E >> 2, ks = E & 3;
    int n = lane & 15, quad = lane >> 4;
    int p = nt * 16 + n;
    unsigned dw[4];
    #pragma unroll
    for (int t2 = 0; t2 < 4; t2++) {
      int c = ks * 16 + quad * 4 + t2;
      dw[t2] = pkbf(c2pr[p * 64 + c], -c2pi[p * 64 + c]);
    }
    ((uint4*)((char*)ws + 197632))[E * 64 + lane] = make_uint4(dw[0], dw[1], dw[2], dw[3]);
  }
}

// LDS dwords: vsh uint[8][516] @0 (4128) | red f32[24][256] @4128 (6144) |
//             dssh f32[48] @10272 ; epilogue bcsh uint[48][68] overlays vsh.
// total 10320 dwords = 41,280 B -> 3 blocks/CU (24 waves/CU).
__global__ __launch_bounds__(512, 6) void pv_main(
    const float* __restrict__ br, const float* __restrict__ bi,
    const float* __restrict__ ws, float* __restrict__ out)
{
  __shared__ __align__(16) unsigned smem[10320];
  unsigned* vsh  = smem;                      // [8][516] bf16-pair
  float*    red  = (float*)(smem + 4128);     // [24][256]
  float*    dssh = (float*)(smem + 10272);    // [48]

  const int bt  = blockIdx.x;
  const int tid = threadIdx.x;
  const float* pr  = br + (size_t)bt * (NCH_ * NBIN_);
  const float* pim = bi + (size_t)bt * (NCH_ * NBIN_);

  // ---- phase A: one bin per thread; v = |x| * unit(conj(x[fm])x[fp]) * rsqrt(trace) ----
  {
    const int f = tid;
    const int fm = (f == 0) ? 0 : ((f == 511) ? 509 : f - 1);
    const int fp = (f == 0) ? 2 : ((f == 511) ? 511 : f + 1);
    float tr = 0.f;
    float t1[8], t2[8];
    #pragma unroll
    for (int c = 0; c < 8; c++) {
      const float* cr = pr + c * 512;
      const float* ci = pim + c * 512;
      float xr = cr[f],   xi = ci[f];
      float xrm = cr[fm], xim = ci[fm];
      float xrp = cr[fp], xip = ci[fp];
      tr = fmaf(xr, xr, tr); tr = fmaf(xi, xi, tr);
      float Gr = fmaf(xrm, xrp,  xim * xip);
      float Gi = fmaf(xrm, xip, -(xim * xrp));
      float am = fmaxf(fmaxf(fabsf(Gr), fabsf(Gi)), 1e-30f);
      float rc = __builtin_amdgcn_rcpf(am);
      float q1 = Gr * rc, q2 = Gi * rc;
      float n2 = fmaf(q1, q1, q2 * q2);
      float rn = __builtin_amdgcn_rsqf(n2);
      bool ok = n2 > 0.f;
      float ur = ok ? q1 * rn : 1.f;
      float ui = ok ? q2 * rn : 0.f;
      float mg = __builtin_amdgcn_sqrtf(fmaf(xr, xr, xi * xi));
      t1[c] = mg * ur; t2[c] = mg * ui;
    }
    float scv = __builtin_amdgcn_rsqf(fmaxf(tr, 1e-20f));
    #pragma unroll
    for (int c = 0; c < 8; c++)
      vsh[c * 516 + f] = pkbf(t1[c] * scv, t2[c] * scv);
  }
  __syncthreads();

  // ---- K-split band GEMM: waves 0-3 take K-half 0, waves 4-7 K-half 1 ----
  const int wv   = tid >> 6;
  const int kh   = wv >> 2;        // K-half
  const int mt   = wv & 3;         // M-tile
  const int lane = tid & 63;
  const int m16  = lane & 15;
  const int quad = lane >> 4;
  const int p    = mt * 16 + m16;
  const int ich  = p >> 3, jch = p & 7;
  const uint4* Avp = (const uint4*)(vsh + ich * 516) + quad;
  const uint4* Bvp = (const uint4*)(vsh + jch * 516) + quad;
  const float4* BFl = ((const float4*)((const char*)ws + 1024)) + lane;

  float4v acc[6];
  #pragma unroll
  for (int g = 0; g < 6; g++) acc[g] = (float4v){0.f, 0.f, 0.f, 0.f};

  #pragma unroll 4
  for (int s = 0; s < 16; s++) {
    const int sg = kh * 16 + s;
    uint4 av = Avp[sg * 4];
    uint4 bv = Bvp[sg * 4];
    float ar[4], ai[4];
    {
      float vr, vi, wr, wi;
      upk(av.x, vr, vi); upk(bv.x, wr, wi);
      ar[0] = fmaf(vr, wr,  vi * wi); ai[0] = fmaf(vi, wr, -(vr * wi));
      upk(av.y, vr, vi); upk(bv.y, wr, wi);
      ar[1] = fmaf(vr, wr,  vi * wi); ai[1] = fmaf(vi, wr, -(vr * wi));
      upk(av.z, vr, vi); upk(bv.z, wr, wi);
      ar[2] = fmaf(vr, wr,  vi * wi); ai[2] = fmaf(vi, wr, -(vr * wi));
      upk(av.w, vr, vi); upk(bv.w, wr, wi);
      ar[3] = fmaf(vr, wr,  vi * wi); ai[3] = fmaf(vi, wr, -(vr * wi));
    }
    uint4 au = make_uint4(pkbf(ar[0], ai[0]), pkbf(ar[1], ai[1]),
                          pkbf(ar[2], ai[2]), pkbf(ar[3], ai[3]));
    short8 afrag = __builtin_bit_cast(short8, au);
    #pragma unroll
    for (int g = 0; g < 6; g++) {
      float4 rawb = BFl[(g * 32 + sg) * 64];
      short8 bfrag = __builtin_bit_cast(short8, rawb);
      acc[g] = __builtin_amdgcn_mfma_f32_16x16x32_bf16(afrag, bfrag, acc[g], 0, 0, 0);
    }
  }

  // K-half 1 publishes partials (SoA: conflict-free)
  if (kh == 1) {
    const int slot = tid & 255;
    #pragma unroll
    for (int g = 0; g < 6; g++)
      #pragma unroll
      for (int r = 0; r < 4; r++)
        red[(g * 4 + r) * 256 + slot] = acc[g][r];
  }
  if (tid < 48) dssh[tid] = (tid < NBAND_) ? ws[tid] : 0.f;
  __syncthreads();

  uint4 eb[4];
  if (kh == 0) {
    const int slot = tid;            // 0..255
    #pragma unroll
    for (int g = 0; g < 6; g++)
      #pragma unroll
      for (int r = 0; r < 4; r++)
        acc[g][r] += red[(g * 4 + r) * 256 + slot];

    // bcsh (bf16 pairs) overlays vsh — all K-loop LDS reads completed at the barrier
    unsigned* bcsh = smem;           // [48][68]
    #pragma unroll
    for (int n = 0; n < 3; n++) {
      uint4 w4 = make_uint4(pkbf(acc[n][0], acc[n + 3][0]),
                            pkbf(acc[n][1], acc[n + 3][1]),
                            pkbf(acc[n][2], acc[n + 3][2]),
                            pkbf(acc[n][3], acc[n + 3][3]));
      *(uint4*)(bcsh + (n * 16 + m16) * 68 + mt * 16 + quad * 4) = w4;
    }
    const uint4* EF = ((const uint4*)((const char*)ws + 197632)) + (mt * 4) * 64 + lane;
    #pragma unroll
    for (int ks = 0; ks < 4; ks++) eb[ks] = EF[ks * 64];
  }
  __syncthreads();

  if (kh == 0) {
    const unsigned* bcsh = smem;
    float4v eacc[3];
    #pragma unroll
    for (int kt = 0; kt < 3; kt++) eacc[kt] = (float4v){0.f, 0.f, 0.f, 0.f};
    #pragma unroll
    for (int ks = 0; ks < 4; ks++) {
      short8 bfr = __builtin_bit_cast(short8, eb[ks]);
      #pragma unroll
      for (int kt = 0; kt < 3; kt++) {
        uint4 a4 = *(const uint4*)(bcsh + (kt * 16 + m16) * 68 + ks * 16 + quad * 4);
        short8 afr = __builtin_bit_cast(short8, a4);
        eacc[kt] = __builtin_amdgcn_mfma_f32_16x16x32_bf16(afr, bfr, eacc[kt], 0, 0, 0);
      }
    }
    float* op = out + (size_t)bt * (NBAND_ * NPV_);
    #pragma unroll
    for (int kt = 0; kt < 3; kt++) {
      #pragma unroll
      for (int r = 0; r < 4; r++) {
        int k = kt * 16 + quad * 4 + r;
        if (k < NBAND_)
          op[k * 64 + mt * 16 + m16] = eacc[kt][r] * dssh[k];
      }
    }
  }
}

// ---------------- IIR: chunked scan, 320 blocks x 256 thr, chunk=25 ----------------
__global__ __launch_bounds__(256) void pv_iir3(float* __restrict__ z,
                                               const float* __restrict__ tau)
{
  __shared__ float gsh[16][16];
  const int pg = blockIdx.x & 3;
  const int bk = blockIdx.x >> 2;
  const int k = bk % NBAND_;
  const int b = bk / NBAND_;
  const float a  = tau[k];
  const float om = 1.0f - a;
  const int c  = threadIdx.x >> 4;
  const int pl = threadIdx.x & 15;
  const int p  = pg * 16 + pl;
  const size_t stride = (size_t)NBAND_ * 64;
  size_t idx0 = (size_t)b * (T_ * NBAND_ * 64) + (size_t)(c * 25) * stride + k * 64 + p;

  float y[25];
  float accv = 0.f;
  #pragma unroll
  for (int i = 0; i < 25; i++) {
    float v = z[idx0 + (size_t)i * stride];
    accv = fmaf(a, accv, om * v);
    y[i] = accv;
  }
  gsh[c][pl] = accv;
  __syncthreads();
  float a2 = a * a, a8 = a2 * a2 * a2 * a2, a16 = a8 * a8;
  float A = a16 * a8 * a;                   // a^25
  float H = 0.f;
  #pragma unroll
  for (int d = 0; d < 15; d++) {
    if (d < c) H = fmaf(A, H, gsh[d][pl]);
  }
  float wp = a;
  #pragma unroll
  for (int i = 0; i < 25; i++) {
    z[idx0 + (size_t)i * stride] = fmaf(wp, H, y[i]);
    wp *= a;
  }
}

extern "C" void kernel_launch(void* const* d_in, const int* in_sizes, int n_in,
                              void* d_out, int out_size, void* d_ws, size_t ws_size,
                              hipStream_t stream)
{
  const float* br   = (const float*)d_in[0];
  const float* bi   = (const float*)d_in[1];
  const float* bmr  = (const float*)d_in[2];
  const float* bmi  = (const float*)d_in[3];
  const float* c2pr = (const float*)d_in[4];
  const float* c2pi = (const float*)d_in[5];
  const float* tau  = (const float*)d_in[6];
  float* out = (float*)d_out;
  float* ws  = (float*)d_ws;

  hipLaunchKernelGGL(pv_prep, dim3(53), dim3(256), 0, stream,
                     bmr, bmi, c2pr, c2pi, ws);
  hipLaunchKernelGGL(pv_main, dim3(B_ * T_), dim3(512), 0, stream,
                     br, bi, ws, out);
  hipLaunchKernelGGL(pv_iir3, dim3(B_ * NBAND_ * 4), dim3(256), 0, stream,
                     out, tau);
}

// Round 6
// 122.419 us; speedup vs baseline: 1.0980x; 1.0980x over previous
//
#include <hip/hip_runtime.h>

#define B_    2
#define T_    400
#define NCH_  8
#define NBIN_ 512
#define NBAND_ 40
#define NPV_  64

using short8  = __attribute__((ext_vector_type(8))) short;
using float4v = __attribute__((ext_vector_type(4))) float;

// bf16 round-to-nearest-even pack of two floats into one dword (lo=x, hi=y)
static __device__ inline unsigned pkbf(float x, float y) {
  union { float f; unsigned u; } a, b;
  a.f = x; b.f = y;
  unsigned ra = a.u + 0x7fffu + ((a.u >> 16) & 1u);
  unsigned rb = b.u + 0x7fffu + ((b.u >> 16) & 1u);
  return (ra >> 16) | (rb & 0xffff0000u);
}
// unpack bf16 pair dword -> two f32 (lo, hi)
static __device__ inline void upk(unsigned u, float& lo, float& hi) {
  union { unsigned q; float f; } a, b;
  a.q = u << 16; b.q = u & 0xffff0000u;
  lo = a.f; hi = b.f;
}

// ws layout (bytes):
//   [0..159]              : dsinv[40] floats
//   [1024, 1024+196608)   : band B-frags: F=((g*3+n)*32+s)*64+lane, uint4 each
//   [197632, 197632+16384): epi  B-frags: E=(nt*4+ks)*64+lane, uint4 each
__global__ __launch_bounds__(256) void pv_prep(
    const float* __restrict__ bmr, const float* __restrict__ bmi,
    const float* __restrict__ c2pr, const float* __restrict__ c2pi,
    float* __restrict__ ws)
{
  const int tid = threadIdx.x;
  const int blk = blockIdx.x;
  if (blk == 0) {
    __shared__ float sds[256];
    int k = tid & 63, part = tid >> 6;
    float s = 0.f;
    if (k < NBAND_) {
      const float* col = bmr + k;
      #pragma unroll 16
      for (int f = part * 128; f < part * 128 + 128; f++) s += col[f * 40];
    }
    sds[tid] = s;
    __syncthreads();
    if (tid < NBAND_) {
      float t = sds[tid] + sds[tid + 64] + sds[tid + 128] + sds[tid + 192];
      ws[tid] = 1.0f / fmaxf(t, 1e-20f);
    }
  } else if (blk <= 48) {
    int F = (blk - 1) * 256 + tid;     // 0..12287
    int l = F & 63;
    int rest = F >> 6;
    int s5 = rest & 31;
    int gn = rest >> 5;
    int n = gn % 3, g = gn / 3;
    int k = n * 16 + (l & 15);
    unsigned dw[4];
    #pragma unroll
    for (int t2 = 0; t2 < 4; t2++) {
      float v0 = 0.f, v1 = 0.f;
      if (k < NBAND_) {
        int kd = s5 * 32 + (l >> 4) * 8 + 2 * t2;
        int f = kd >> 1;
        if (g == 0) { v0 = bmr[f * 40 + k]; v1 = -bmi[f * 40 + k]; }
        else        { v0 = bmi[f * 40 + k]; v1 =  bmr[f * 40 + k]; }
      }
      dw[t2] = pkbf(v0, v1);
    }
    ((uint4*)((char*)ws + 1024))[F] = make_uint4(dw[0], dw[1], dw[2], dw[3]);
  } else {
    int F2 = (blk - 49) * 256 + tid;   // 0..1023
    int lane = F2 & 63, E = F2 >> 6;
    int nt = E >> 2, ks = E & 3;
    int n = lane & 15, quad = lane >> 4;
    int p = nt * 16 + n;
    unsigned dw[4];
    #pragma unroll
    for (int t2 = 0; t2 < 4; t2++) {
      int c = ks * 16 + quad * 4 + t2;
      dw[t2] = pkbf(c2pr[p * 64 + c], -c2pi[p * 64 + c]);
    }
    ((uint4*)((char*)ws + 197632))[E * 64 + lane] = make_uint4(dw[0], dw[1], dw[2], dw[3]);
  }
}

// LDS dwords: vsh uint[8][516] @0 (4128) | dssh f32[48] @4128
// epilogue bcsh uint[48][68] overlays vsh. total 4176 dw = 16,704 B.
__global__ __launch_bounds__(256, 4) void pv_main(
    const float* __restrict__ br, const float* __restrict__ bi,
    const float* __restrict__ ws, float* __restrict__ out)
{
  __shared__ __align__(16) unsigned smem[4176];
  unsigned* vsh  = smem;                      // [8][516] bf16-pair
  float*    dssh = (float*)(smem + 4128);     // [48]

  const int bt  = blockIdx.x;
  const int tid = threadIdx.x;
  const float* pr  = br + (size_t)bt * (NCH_ * NBIN_);
  const float* pim = bi + (size_t)bt * (NCH_ * NBIN_);

  const int mt   = tid >> 6;       // wave id = M-tile
  const int lane = tid & 63;
  const int m16  = lane & 15;
  const int quad = lane >> 4;
  const int p    = mt * 16 + m16;
  const int ich  = p >> 3, jch = p & 7;
  const float4* BFl = ((const float4*)((const char*)ws + 1024)) + lane;

  // early B-frag prefetch for s=0,1 — overlaps phase A
  float4 BFp[2][6];
  #pragma unroll
  for (int g = 0; g < 6; g++) BFp[0][g] = BFl[(g * 32 + 0) * 64];
  #pragma unroll
  for (int g = 0; g < 6; g++) BFp[1][g] = BFl[(g * 32 + 1) * 64];

  // ---- phase A: 2 bins per thread ----
  #pragma unroll
  for (int fs = 0; fs < 2; fs++) {
    const int f = fs * 256 + tid;
    const int fm = (f == 0) ? 0 : ((f == 511) ? 509 : f - 1);
    const int fp = (f == 0) ? 2 : ((f == 511) ? 511 : f + 1);
    float tr = 0.f;
    float t1[8], t2[8];
    #pragma unroll
    for (int c = 0; c < 8; c++) {
      const float* cr = pr + c * 512;
      const float* ci = pim + c * 512;
      float xr = cr[f],   xi = ci[f];
      float xrm = cr[fm], xim = ci[fm];
      float xrp = cr[fp], xip = ci[fp];
      tr = fmaf(xr, xr, tr); tr = fmaf(xi, xi, tr);
      float Gr = fmaf(xrm, xrp,  xim * xip);
      float Gi = fmaf(xrm, xip, -(xim * xrp));
      float am = fmaxf(fmaxf(fabsf(Gr), fabsf(Gi)), 1e-30f);
      float rc = __builtin_amdgcn_rcpf(am);
      float q1 = Gr * rc, q2 = Gi * rc;
      float n2 = fmaf(q1, q1, q2 * q2);
      float rn = __builtin_amdgcn_rsqf(n2);
      bool ok = n2 > 0.f;
      float ur = ok ? q1 * rn : 1.f;
      float ui = ok ? q2 * rn : 0.f;
      float mg = __builtin_amdgcn_sqrtf(fmaf(xr, xr, xi * xi));
      t1[c] = mg * ur; t2[c] = mg * ui;
    }
    float scv = __builtin_amdgcn_rsqf(fmaxf(tr, 1e-20f));
    #pragma unroll
    for (int c = 0; c < 8; c++)
      vsh[c * 516 + f] = pkbf(t1[c] * scv, t2[c] * scv);
  }
  __syncthreads();

  // ---- band GEMM, full K per wave, depth-2 pipelined ----
  const uint4* Avp = (const uint4*)(vsh + ich * 516) + quad;
  const uint4* Bvp = (const uint4*)(vsh + jch * 516) + quad;

  float4v acc[6];
  #pragma unroll
  for (int g = 0; g < 6; g++) acc[g] = (float4v){0.f, 0.f, 0.f, 0.f};

  uint4 Apre[2], Bpre[2];
  Apre[0] = Avp[0]; Bpre[0] = Bvp[0];
  Apre[1] = Avp[4]; Bpre[1] = Bvp[4];

  #pragma unroll
  for (int s = 0; s < 32; s++) {
    const int cs = s & 1;
    uint4 av = Apre[cs], bv = Bpre[cs];
    float4 cb[6];
    #pragma unroll
    for (int g = 0; g < 6; g++) cb[g] = BFp[cs][g];
    if (s + 2 < 32) {                 // prefetch distance 2 (SSA renaming kills WAR)
      Apre[cs] = Avp[(s + 2) * 4];
      Bpre[cs] = Bvp[(s + 2) * 4];
      #pragma unroll
      for (int g = 0; g < 6; g++) BFp[cs][g] = BFl[(g * 32 + s + 2) * 64];
    }
    float ar[4], ai[4];
    {
      float vr, vi, wr, wi;
      upk(av.x, vr, vi); upk(bv.x, wr, wi);
      ar[0] = fmaf(vr, wr,  vi * wi); ai[0] = fmaf(vi, wr, -(vr * wi));
      upk(av.y, vr, vi); upk(bv.y, wr, wi);
      ar[1] = fmaf(vr, wr,  vi * wi); ai[1] = fmaf(vi, wr, -(vr * wi));
      upk(av.z, vr, vi); upk(bv.z, wr, wi);
      ar[2] = fmaf(vr, wr,  vi * wi); ai[2] = fmaf(vi, wr, -(vr * wi));
      upk(av.w, vr, vi); upk(bv.w, wr, wi);
      ar[3] = fmaf(vr, wr,  vi * wi); ai[3] = fmaf(vi, wr, -(vr * wi));
    }
    uint4 au = make_uint4(pkbf(ar[0], ai[0]), pkbf(ar[1], ai[1]),
                          pkbf(ar[2], ai[2]), pkbf(ar[3], ai[3]));
    short8 afrag = __builtin_bit_cast(short8, au);
    #pragma unroll
    for (int g = 0; g < 6; g++) {
      short8 bfrag = __builtin_bit_cast(short8, cb[g]);
      acc[g] = __builtin_amdgcn_mfma_f32_16x16x32_bf16(afrag, bfrag, acc[g], 0, 0, 0);
    }
  }

  // epilogue B-frags + dsinv (no vsh dependency — issue before barrier)
  const uint4* EF = ((const uint4*)((const char*)ws + 197632)) + (mt * 4) * 64 + lane;
  uint4 eb[4];
  #pragma unroll
  for (int ks = 0; ks < 4; ks++) eb[ks] = EF[ks * 64];
  if (tid < 48) dssh[tid] = (tid < NBAND_) ? ws[tid] : 0.f;

  // ---- epilogue GEMM: pv[k][p] = Re(sum_c c2p[p][c]*bc[k][c]) ----
  __syncthreads();                    // all vsh reads done; overlay bcsh
  unsigned* bcsh = smem;              // [48][68] bf16-pair
  #pragma unroll
  for (int n = 0; n < 3; n++) {
    uint4 w4 = make_uint4(pkbf(acc[n][0], acc[n + 3][0]),
                          pkbf(acc[n][1], acc[n + 3][1]),
                          pkbf(acc[n][2], acc[n + 3][2]),
                          pkbf(acc[n][3], acc[n + 3][3]));
    *(uint4*)(bcsh + (n * 16 + m16) * 68 + mt * 16 + quad * 4) = w4;
  }
  __syncthreads();

  float4v eacc[3];
  #pragma unroll
  for (int kt = 0; kt < 3; kt++) eacc[kt] = (float4v){0.f, 0.f, 0.f, 0.f};
  #pragma unroll
  for (int ks = 0; ks < 4; ks++) {
    short8 bfr = __builtin_bit_cast(short8, eb[ks]);
    #pragma unroll
    for (int kt = 0; kt < 3; kt++) {
      uint4 a4 = *(const uint4*)(bcsh + (kt * 16 + m16) * 68 + ks * 16 + quad * 4);
      short8 afr = __builtin_bit_cast(short8, a4);
      eacc[kt] = __builtin_amdgcn_mfma_f32_16x16x32_bf16(afr, bfr, eacc[kt], 0, 0, 0);
    }
  }
  float* op = out + (size_t)bt * (NBAND_ * NPV_);
  #pragma unroll
  for (int kt = 0; kt < 3; kt++) {
    #pragma unroll
    for (int r = 0; r < 4; r++) {
      int k = kt * 16 + quad * 4 + r;
      if (k < NBAND_)
        op[k * 64 + mt * 16 + m16] = eacc[kt][r] * dssh[k];
    }
  }
}

// ---------------- IIR: chunked scan, 320 blocks x 256 thr, chunk=25 ----------------
__global__ __launch_bounds__(256) void pv_iir3(float* __restrict__ z,
                                               const float* __restrict__ tau)
{
  __shared__ float gsh[16][16];
  const int pg = blockIdx.x & 3;
  const int bk = blockIdx.x >> 2;
  const int k = bk % NBAND_;
  const int b = bk / NBAND_;
  const float a  = tau[k];
  const float om = 1.0f - a;
  const int c  = threadIdx.x >> 4;
  const int pl = threadIdx.x & 15;
  const int p  = pg * 16 + pl;
  const size_t stride = (size_t)NBAND_ * 64;
  size_t idx0 = (size_t)b * (T_ * NBAND_ * 64) + (size_t)(c * 25) * stride + k * 64 + p;

  float y[25];
  float accv = 0.f;
  #pragma unroll
  for (int i = 0; i < 25; i++) {
    float v = z[idx0 + (size_t)i * stride];
    accv = fmaf(a, accv, om * v);
    y[i] = accv;
  }
  gsh[c][pl] = accv;
  __syncthreads();
  float a2 = a * a, a8 = a2 * a2 * a2 * a2, a16 = a8 * a8;
  float A = a16 * a8 * a;                   // a^25
  float H = 0.f;
  #pragma unroll
  for (int d = 0; d < 15; d++) {
    if (d < c) H = fmaf(A, H, gsh[d][pl]);
  }
  float wp = a;
  #pragma unroll
  for (int i = 0; i < 25; i++) {
    z[idx0 + (size_t)i * stride] = fmaf(wp, H, y[i]);
    wp *= a;
  }
}

extern "C" void kernel_launch(void* const* d_in, const int* in_sizes, int n_in,
                              void* d_out, int out_size, void* d_ws, size_t ws_size,
                              hipStream_t stream)
{
  const float* br   = (const float*)d_in[0];
  const float* bi   = (const float*)d_in[1];
  const float* bmr  = (const float*)d_in[2];
  const float* bmi  = (const float*)d_in[3];
  const float* c2pr = (const float*)d_in[4];
  const float* c2pi = (const float*)d_in[5];
  const float* tau  = (const float*)d_in[6];
  float* out = (float*)d_out;
  float* ws  = (float*)d_ws;

  hipLaunchKernelGGL(pv_prep, dim3(53), dim3(256), 0, stream,
                     bmr, bmi, c2pr, c2pi, ws);
  hipLaunchKernelGGL(pv_main, dim3(B_ * T_), dim3(256), 0, stream,
                     br, bi, ws, out);
  hipLaunchKernelGGL(pv_iir3, dim3(B_ * NBAND_ * 4), dim3(256), 0, stream,
                     out, tau);
}

// Round 7
// 121.741 us; speedup vs baseline: 1.1041x; 1.0056x over previous
//
#include <hip/hip_runtime.h>

#define B_    2
#define T_    400
#define NCH_  8
#define NBIN_ 512
#define NBAND_ 40
#define NPV_  64

using short8  = __attribute__((ext_vector_type(8))) short;
using float4v = __attribute__((ext_vector_type(4))) float;

// bf16 round-to-nearest-even pack of two floats into one dword (lo=x, hi=y)
static __device__ inline unsigned pkbf(float x, float y) {
  union { float f; unsigned u; } a, b;
  a.f = x; b.f = y;
  unsigned ra = a.u + 0x7fffu + ((a.u >> 16) & 1u);
  unsigned rb = b.u + 0x7fffu + ((b.u >> 16) & 1u);
  return (ra >> 16) | (rb & 0xffff0000u);
}
// unpack bf16 pair dword -> two f32 (lo, hi)
static __device__ inline void upk(unsigned u, float& lo, float& hi) {
  union { unsigned q; float f; } a, b;
  a.q = u << 16; b.q = u & 0xffff0000u;
  lo = a.f; hi = b.f;
}

// ws layout (bytes):
//   [0..159]              : dsinv[40] floats
//   [1024, 1024+196608)   : band B-frags, s-major: F=(s*6+g)*64+lane, uint4 each
//   [197632, 197632+16384): epi  B-frags: E=(nt*4+ks)*64+lane, uint4 each
__global__ __launch_bounds__(256) void pv_prep(
    const float* __restrict__ bmr, const float* __restrict__ bmi,
    const float* __restrict__ c2pr, const float* __restrict__ c2pi,
    float* __restrict__ ws)
{
  const int tid = threadIdx.x;
  const int blk = blockIdx.x;
  if (blk == 0) {
    __shared__ float sds[256];
    int k = tid & 63, part = tid >> 6;
    float s = 0.f;
    if (k < NBAND_) {
      const float* col = bmr + k;
      #pragma unroll 16
      for (int f = part * 128; f < part * 128 + 128; f++) s += col[f * 40];
    }
    sds[tid] = s;
    __syncthreads();
    if (tid < NBAND_) {
      float t = sds[tid] + sds[tid + 64] + sds[tid + 128] + sds[tid + 192];
      ws[tid] = 1.0f / fmaxf(t, 1e-20f);
    }
  } else if (blk <= 48) {
    int F = (blk - 1) * 256 + tid;     // 0..12287
    int l = F & 63;
    int fid = F >> 6;                  // 0..191 = s*6 + gg
    int s5 = fid / 6;
    int gg = fid - s5 * 6;
    int g = gg / 3, n = gg - g * 3;
    int k = n * 16 + (l & 15);
    unsigned dw[4];
    #pragma unroll
    for (int t2 = 0; t2 < 4; t2++) {
      float v0 = 0.f, v1 = 0.f;
      if (k < NBAND_) {
        int kd = s5 * 32 + (l >> 4) * 8 + 2 * t2;
        int f = kd >> 1;
        if (g == 0) { v0 = bmr[f * 40 + k]; v1 = -bmi[f * 40 + k]; }
        else        { v0 = bmi[f * 40 + k]; v1 =  bmr[f * 40 + k]; }
      }
      dw[t2] = pkbf(v0, v1);
    }
    ((uint4*)((char*)ws + 1024))[F] = make_uint4(dw[0], dw[1], dw[2], dw[3]);
  } else {
    int F2 = (blk - 49) * 256 + tid;   // 0..1023
    int lane = F2 & 63, E = F2 >> 6;
    int nt = E >> 2, ks = E & 3;
    int n = lane & 15, quad = lane >> 4;
    int p = nt * 16 + n;
    unsigned dw[4];
    #pragma unroll
    for (int t2 = 0; t2 < 4; t2++) {
      int c = ks * 16 + quad * 4 + t2;
      dw[t2] = pkbf(c2pr[p * 64 + c], -c2pi[p * 64 + c]);
    }
    ((uint4*)((char*)ws + 197632))[E * 64 + lane] = make_uint4(dw[0], dw[1], dw[2], dw[3]);
  }
}

// LDS dwords: vsh uint[8][516] @0 (4128) | dssh f32[48] @4128
// epilogue bcsh uint[48][68] overlays vsh. total 4176 dw = 16,704 B.
// amdgpu_waves_per_eu(4,4): grid is 800 blocks -> 3.1 waves/SIMD max; pin the
// scheduler's occupancy target so it keeps prefetch registers live (R6's VGPR=52
// showed it crushed the pipeline to chase 8-wave occupancy we can't reach).
__global__ __launch_bounds__(256)
__attribute__((amdgpu_waves_per_eu(4, 4)))
void pv_main(
    const float* __restrict__ br, const float* __restrict__ bi,
    const float* __restrict__ ws, float* __restrict__ out)
{
  __shared__ __align__(16) unsigned smem[4176];
  unsigned* vsh  = smem;                      // [8][516] bf16-pair
  float*    dssh = (float*)(smem + 4128);     // [48]

  const int bt  = blockIdx.x;
  const int tid = threadIdx.x;
  const float* pr  = br + (size_t)bt * (NCH_ * NBIN_);
  const float* pim = bi + (size_t)bt * (NCH_ * NBIN_);

  const int mt   = tid >> 6;       // wave id = M-tile
  const int lane = tid & 63;
  const int m16  = lane & 15;
  const int quad = lane >> 4;
  const int p    = mt * 16 + m16;
  const int ich  = p >> 3, jch = p & 7;
  const float4* BFl = ((const float4*)((const char*)ws + 1024)) + lane;

  // early B-frag prefetch for s=0,1,2 — overlaps phase A
  float4 BFp[3][6];
  #pragma unroll
  for (int d = 0; d < 3; d++)
    #pragma unroll
    for (int g = 0; g < 6; g++) BFp[d][g] = BFl[(d * 6 + g) * 64];

  // ---- phase A: 2 bins per thread ----
  #pragma unroll
  for (int fs = 0; fs < 2; fs++) {
    const int f = fs * 256 + tid;
    const int fm = (f == 0) ? 0 : ((f == 511) ? 509 : f - 1);
    const int fp = (f == 0) ? 2 : ((f == 511) ? 511 : f + 1);
    float tr = 0.f;
    float t1[8], t2[8];
    #pragma unroll
    for (int c = 0; c < 8; c++) {
      const float* cr = pr + c * 512;
      const float* ci = pim + c * 512;
      float xr = cr[f],   xi = ci[f];
      float xrm = cr[fm], xim = ci[fm];
      float xrp = cr[fp], xip = ci[fp];
      tr = fmaf(xr, xr, tr); tr = fmaf(xi, xi, tr);
      float Gr = fmaf(xrm, xrp,  xim * xip);
      float Gi = fmaf(xrm, xip, -(xim * xrp));
      float am = fmaxf(fmaxf(fabsf(Gr), fabsf(Gi)), 1e-30f);
      float rc = __builtin_amdgcn_rcpf(am);
      float q1 = Gr * rc, q2 = Gi * rc;
      float n2 = fmaf(q1, q1, q2 * q2);
      float rn = __builtin_amdgcn_rsqf(n2);
      bool ok = n2 > 0.f;
      float ur = ok ? q1 * rn : 1.f;
      float ui = ok ? q2 * rn : 0.f;
      float mg = __builtin_amdgcn_sqrtf(fmaf(xr, xr, xi * xi));
      t1[c] = mg * ur; t2[c] = mg * ui;
    }
    float scv = __builtin_amdgcn_rsqf(fmaxf(tr, 1e-20f));
    #pragma unroll
    for (int c = 0; c < 8; c++)
      vsh[c * 516 + f] = pkbf(t1[c] * scv, t2[c] * scv);
  }
  __syncthreads();

  // ---- band GEMM, full K per wave; global prefetch dist 3, LDS dist 2 ----
  const uint4* Avp = (const uint4*)(vsh + ich * 516) + quad;
  const uint4* Bvp = (const uint4*)(vsh + jch * 516) + quad;

  float4v acc[6];
  #pragma unroll
  for (int g = 0; g < 6; g++) acc[g] = (float4v){0.f, 0.f, 0.f, 0.f};

  uint4 Apre[2], Bpre[2];
  Apre[0] = Avp[0]; Bpre[0] = Bvp[0];
  Apre[1] = Avp[4]; Bpre[1] = Bvp[4];

  #pragma unroll
  for (int s = 0; s < 32; s++) {
    const int c2 = s & 1;
    const int c3 = s % 3;
    uint4 av = Apre[c2], bv = Bpre[c2];
    float4 cb[6];
    #pragma unroll
    for (int g = 0; g < 6; g++) cb[g] = BFp[c3][g];
    if (s + 2 < 32) {
      Apre[c2] = Avp[(s + 2) * 4];
      Bpre[c2] = Bvp[(s + 2) * 4];
    }
    if (s + 3 < 32) {
      #pragma unroll
      for (int g = 0; g < 6; g++) BFp[c3][g] = BFl[((s + 3) * 6 + g) * 64];
    }
    float ar[4], ai[4];
    {
      float vr, vi, wr, wi;
      upk(av.x, vr, vi); upk(bv.x, wr, wi);
      ar[0] = fmaf(vr, wr,  vi * wi); ai[0] = fmaf(vi, wr, -(vr * wi));
      upk(av.y, vr, vi); upk(bv.y, wr, wi);
      ar[1] = fmaf(vr, wr,  vi * wi); ai[1] = fmaf(vi, wr, -(vr * wi));
      upk(av.z, vr, vi); upk(bv.z, wr, wi);
      ar[2] = fmaf(vr, wr,  vi * wi); ai[2] = fmaf(vi, wr, -(vr * wi));
      upk(av.w, vr, vi); upk(bv.w, wr, wi);
      ar[3] = fmaf(vr, wr,  vi * wi); ai[3] = fmaf(vi, wr, -(vr * wi));
    }
    uint4 au = make_uint4(pkbf(ar[0], ai[0]), pkbf(ar[1], ai[1]),
                          pkbf(ar[2], ai[2]), pkbf(ar[3], ai[3]));
    short8 afrag = __builtin_bit_cast(short8, au);
    #pragma unroll
    for (int g = 0; g < 6; g++) {
      short8 bfrag = __builtin_bit_cast(short8, cb[g]);
      acc[g] = __builtin_amdgcn_mfma_f32_16x16x32_bf16(afrag, bfrag, acc[g], 0, 0, 0);
    }
  }

  // epilogue B-frags + dsinv (no vsh dependency — issue before barrier)
  const uint4* EF = ((const uint4*)((const char*)ws + 197632)) + (mt * 4) * 64 + lane;
  uint4 eb[4];
  #pragma unroll
  for (int ks = 0; ks < 4; ks++) eb[ks] = EF[ks * 64];
  if (tid < 48) dssh[tid] = (tid < NBAND_) ? ws[tid] : 0.f;

  // ---- epilogue GEMM: pv[k][p] = Re(sum_c c2p[p][c]*bc[k][c]) ----
  __syncthreads();                    // all vsh reads done; overlay bcsh
  unsigned* bcsh = smem;              // [48][68] bf16-pair
  #pragma unroll
  for (int n = 0; n < 3; n++) {
    uint4 w4 = make_uint4(pkbf(acc[n][0], acc[n + 3][0]),
                          pkbf(acc[n][1], acc[n + 3][1]),
                          pkbf(acc[n][2], acc[n + 3][2]),
                          pkbf(acc[n][3], acc[n + 3][3]));
    *(uint4*)(bcsh + (n * 16 + m16) * 68 + mt * 16 + quad * 4) = w4;
  }
  __syncthreads();

  float4v eacc[3];
  #pragma unroll
  for (int kt = 0; kt < 3; kt++) eacc[kt] = (float4v){0.f, 0.f, 0.f, 0.f};
  #pragma unroll
  for (int ks = 0; ks < 4; ks++) {
    short8 bfr = __builtin_bit_cast(short8, eb[ks]);
    #pragma unroll
    for (int kt = 0; kt < 3; kt++) {
      uint4 a4 = *(const uint4*)(bcsh + (kt * 16 + m16) * 68 + ks * 16 + quad * 4);
      short8 afr = __builtin_bit_cast(short8, a4);
      eacc[kt] = __builtin_amdgcn_mfma_f32_16x16x32_bf16(afr, bfr, eacc[kt], 0, 0, 0);
    }
  }
  float* op = out + (size_t)bt * (NBAND_ * NPV_);
  #pragma unroll
  for (int kt = 0; kt < 3; kt++) {
    #pragma unroll
    for (int r = 0; r < 4; r++) {
      int k = kt * 16 + quad * 4 + r;
      if (k < NBAND_)
        op[k * 64 + mt * 16 + m16] = eacc[kt][r] * dssh[k];
    }
  }
}

// ---------------- IIR: chunked scan, 320 blocks x 256 thr, chunk=25 ----------------
__global__ __launch_bounds__(256) void pv_iir3(float* __restrict__ z,
                                               const float* __restrict__ tau)
{
  __shared__ float gsh[16][16];
  const int pg = blockIdx.x & 3;
  const int bk = blockIdx.x >> 2;
  const int k = bk % NBAND_;
  const int b = bk / NBAND_;
  const float a  = tau[k];
  const float om = 1.0f - a;
  const int c  = threadIdx.x >> 4;
  const int pl = threadIdx.x & 15;
  const int p  = pg * 16 + pl;
  const size_t stride = (size_t)NBAND_ * 64;
  size_t idx0 = (size_t)b * (T_ * NBAND_ * 64) + (size_t)(c * 25) * stride + k * 64 + p;

  float y[25];
  float accv = 0.f;
  #pragma unroll
  for (int i = 0; i < 25; i++) {
    float v = z[idx0 + (size_t)i * stride];
    accv = fmaf(a, accv, om * v);
    y[i] = accv;
  }
  gsh[c][pl] = accv;
  __syncthreads();
  float a2 = a * a, a8 = a2 * a2 * a2 * a2, a16 = a8 * a8;
  float A = a16 * a8 * a;                   // a^25
  float H = 0.f;
  #pragma unroll
  for (int d = 0; d < 15; d++) {
    if (d < c) H = fmaf(A, H, gsh[d][pl]);
  }
  float wp = a;
  #pragma unroll
  for (int i = 0; i < 25; i++) {
    z[idx0 + (size_t)i * stride] = fmaf(wp, H, y[i]);
    wp *= a;
  }
}

extern "C" void kernel_launch(void* const* d_in, const int* in_sizes, int n_in,
                              void* d_out, int out_size, void* d_ws, size_t ws_size,
                              hipStream_t stream)
{
  const float* br   = (const float*)d_in[0];
  const float* bi   = (const float*)d_in[1];
  const float* bmr  = (const float*)d_in[2];
  const float* bmi  = (const float*)d_in[3];
  const float* c2pr = (const float*)d_in[4];
  const float* c2pi = (const float*)d_in[5];
  const float* tau  = (const float*)d_in[6];
  float* out = (float*)d_out;
  float* ws  = (float*)d_ws;

  hipLaunchKernelGGL(pv_prep, dim3(53), dim3(256), 0, stream,
                     bmr, bmi, c2pr, c2pi, ws);
  hipLaunchKernelGGL(pv_main, dim3(B_ * T_), dim3(256), 0, stream,
                     br, bi, ws, out);
  hipLaunchKernelGGL(pv_iir3, dim3(B_ * NBAND_ * 4), dim3(256), 0, stream,
                     out, tau);
}

// Round 8
// 117.668 us; speedup vs baseline: 1.1423x; 1.0346x over previous
//
#include <hip/hip_runtime.h>

#define B_    2
#define T_    400
#define NCH_  8
#define NBIN_ 512
#define NBAND_ 40
#define NPV_  64

using short8  = __attribute__((ext_vector_type(8))) short;
using float4v = __attribute__((ext_vector_type(4))) float;

// bf16 round-to-nearest-even pack of two floats into one dword (lo=x, hi=y)
static __device__ inline unsigned pkbf(float x, float y) {
  union { float f; unsigned u; } a, b;
  a.f = x; b.f = y;
  unsigned ra = a.u + 0x7fffu + ((a.u >> 16) & 1u);
  unsigned rb = b.u + 0x7fffu + ((b.u >> 16) & 1u);
  return (ra >> 16) | (rb & 0xffff0000u);
}
// unpack bf16 pair dword -> two f32 (lo, hi)
static __device__ inline void upk(unsigned u, float& lo, float& hi) {
  union { unsigned q; float f; } a, b;
  a.q = u << 16; b.q = u & 0xffff0000u;
  lo = a.f; hi = b.f;
}
// {lo:ar, hi:-ai} -> {lo:ai, hi:ar}  (sign-flip hi, swap halves)
static __device__ inline unsigned swapvar(unsigned u) {
  unsigned r = u ^ 0x80000000u;
  return (r >> 16) | (r << 16);
}

// ws layout (bytes):
//   [0..159]              : dsinv[40] floats
//   [1024, 1024+98304)    : band B-frags, s-major, stored ONCE (N=48):
//                           F=(s*3+n)*64+lane, uint4; dword t = {bmr[f,k], bmi[f,k]},
//                           f = s*16 + (lane>>4)*4 + t, k = n*16 + (lane&15)
//   [197632, 197632+16384): epi B-frags: E=(nt*4+ks)*64+lane, uint4 each
__global__ __launch_bounds__(256) void pv_prep(
    const float* __restrict__ bmr, const float* __restrict__ bmi,
    const float* __restrict__ c2pr, const float* __restrict__ c2pi,
    float* __restrict__ ws)
{
  const int tid = threadIdx.x;
  const int blk = blockIdx.x;
  if (blk == 0) {
    __shared__ float sds[256];
    int k = tid & 63, part = tid >> 6;
    float s = 0.f;
    if (k < NBAND_) {
      const float* col = bmr + k;
      #pragma unroll 16
      for (int f = part * 128; f < part * 128 + 128; f++) s += col[f * 40];
    }
    sds[tid] = s;
    __syncthreads();
    if (tid < NBAND_) {
      float t = sds[tid] + sds[tid + 64] + sds[tid + 128] + sds[tid + 192];
      ws[tid] = 1.0f / fmaxf(t, 1e-20f);
    }
  } else if (blk <= 24) {
    int F = (blk - 1) * 256 + tid;     // 0..6143
    int l = F & 63;
    int fid = F >> 6;                  // 0..95 = s*3 + n
    int s5 = fid / 3;
    int n = fid - s5 * 3;
    int k = n * 16 + (l & 15);
    int quad = l >> 4;
    unsigned dw[4];
    #pragma unroll
    for (int t2 = 0; t2 < 4; t2++) {
      float v0 = 0.f, v1 = 0.f;
      if (k < NBAND_) {
        int f = s5 * 16 + quad * 4 + t2;
        v0 = bmr[f * 40 + k]; v1 = bmi[f * 40 + k];
      }
      dw[t2] = pkbf(v0, v1);
    }
    ((uint4*)((char*)ws + 1024))[F] = make_uint4(dw[0], dw[1], dw[2], dw[3]);
  } else {
    int F2 = (blk - 25) * 256 + tid;   // 0..1023
    int lane = F2 & 63, E = F2 >> 6;
    int nt = E >> 2, ks = E & 3;
    int n = lane & 15, quad = lane >> 4;
    int p = nt * 16 + n;
    unsigned dw[4];
    #pragma unroll
    for (int t2 = 0; t2 < 4; t2++) {
      int c = ks * 16 + quad * 4 + t2;
      dw[t2] = pkbf(c2pr[p * 64 + c], -c2pi[p * 64 + c]);
    }
    ((uint4*)((char*)ws + 197632))[E * 64 + lane] = make_uint4(dw[0], dw[1], dw[2], dw[3]);
  }
}

// LDS dwords: vsh uint[8][516] @0 (4128) | dssh f32[48] @4128
// epilogue bcsh uint[48][68] overlays vsh. total 4176 dw = 16,704 B.
// waves_per_eu(3,4): grid is 800 blocks -> 3.1 waves/SIMD; VGPR cap ~170 so
// the scheduler keeps the prefetch pipeline live instead of chasing 8-wave
// occupancy we can never reach (R6: VGPR crushed to 52, pipeline dead).
__global__ __launch_bounds__(256)
__attribute__((amdgpu_waves_per_eu(3, 4)))
void pv_main(
    const float* __restrict__ br, const float* __restrict__ bi,
    const float* __restrict__ ws, float* __restrict__ out)
{
  __shared__ __align__(16) unsigned smem[4176];
  unsigned* vsh  = smem;                      // [8][516] bf16-pair
  float*    dssh = (float*)(smem + 4128);     // [48]

  const int bt  = blockIdx.x;
  const int tid = threadIdx.x;
  const float* pr  = br + (size_t)bt * (NCH_ * NBIN_);
  const float* pim = bi + (size_t)bt * (NCH_ * NBIN_);

  const int mt   = tid >> 6;       // wave id = M-tile
  const int lane = tid & 63;
  const int m16  = lane & 15;
  const int quad = lane >> 4;
  const int p    = mt * 16 + m16;
  const int ich  = p >> 3, jch = p & 7;
  const uint4* BFl = ((const uint4*)((const char*)ws + 1024)) + lane;

  // B-frag prefetch for s=0..3 — overlaps phase A
  uint4 BFp[4][3];
  #pragma unroll
  for (int d = 0; d < 4; d++)
    #pragma unroll
    for (int n = 0; n < 3; n++) BFp[d][n] = BFl[(d * 3 + n) * 64];

  // ---- phase A: 2 bins per thread ----
  #pragma unroll
  for (int fs = 0; fs < 2; fs++) {
    const int f = fs * 256 + tid;
    const int fm = (f == 0) ? 0 : ((f == 511) ? 509 : f - 1);
    const int fp = (f == 0) ? 2 : ((f == 511) ? 511 : f + 1);
    float tr = 0.f;
    float t1[8], t2[8];
    #pragma unroll
    for (int c = 0; c < 8; c++) {
      const float* cr = pr + c * 512;
      const float* ci = pim + c * 512;
      float xr = cr[f],   xi = ci[f];
      float xrm = cr[fm], xim = ci[fm];
      float xrp = cr[fp], xip = ci[fp];
      tr = fmaf(xr, xr, tr); tr = fmaf(xi, xi, tr);
      float Gr = fmaf(xrm, xrp,  xim * xip);
      float Gi = fmaf(xrm, xip, -(xim * xrp));
      float am = fmaxf(fmaxf(fabsf(Gr), fabsf(Gi)), 1e-30f);
      float rc = __builtin_amdgcn_rcpf(am);
      float q1 = Gr * rc, q2 = Gi * rc;
      float n2 = fmaf(q1, q1, q2 * q2);
      float rn = __builtin_amdgcn_rsqf(n2);
      bool ok = n2 > 0.f;
      float ur = ok ? q1 * rn : 1.f;
      float ui = ok ? q2 * rn : 0.f;
      float mg = __builtin_amdgcn_sqrtf(fmaf(xr, xr, xi * xi));
      t1[c] = mg * ur; t2[c] = mg * ui;
    }
    float scv = __builtin_amdgcn_rsqf(fmaxf(tr, 1e-20f));
    #pragma unroll
    for (int c = 0; c < 8; c++)
      vsh[c * 516 + f] = pkbf(t1[c] * scv, t2[c] * scv);
  }
  __syncthreads();

  // ---- band GEMM: B stored once (N=48), two A variants (C_r and C_i) ----
  const uint4* Avp = (const uint4*)(vsh + ich * 516) + quad;
  const uint4* Bvp = (const uint4*)(vsh + jch * 516) + quad;

  float4v acc[6];                  // [0..2]=real cols, [3..5]=imag cols
  #pragma unroll
  for (int g = 0; g < 6; g++) acc[g] = (float4v){0.f, 0.f, 0.f, 0.f};

  uint4 Apre[2], Bpre[2];
  Apre[0] = Avp[0]; Bpre[0] = Bvp[0];
  Apre[1] = Avp[4]; Bpre[1] = Bvp[4];

  #pragma unroll
  for (int s = 0; s < 32; s++) {
    const int c2 = s & 1;
    const int c4 = s & 3;
    uint4 av = Apre[c2], bv = Bpre[c2];
    uint4 cb[3];
    #pragma unroll
    for (int n = 0; n < 3; n++) cb[n] = BFp[c4][n];
    if (s + 2 < 32) {
      Apre[c2] = Avp[(s + 2) * 4];
      Bpre[c2] = Bvp[(s + 2) * 4];
    }
    if (s + 4 < 32) {
      #pragma unroll
      for (int n = 0; n < 3; n++) BFp[c4][n] = BFl[((s + 4) * 3 + n) * 64];
    }
    float ar[4], ai[4];
    {
      float vr, vi, wr, wi;
      upk(av.x, vr, vi); upk(bv.x, wr, wi);
      ar[0] = fmaf(vr, wr,  vi * wi); ai[0] = fmaf(vi, wr, -(vr * wi));
      upk(av.y, vr, vi); upk(bv.y, wr, wi);
      ar[1] = fmaf(vr, wr,  vi * wi); ai[1] = fmaf(vi, wr, -(vr * wi));
      upk(av.z, vr, vi); upk(bv.z, wr, wi);
      ar[2] = fmaf(vr, wr,  vi * wi); ai[2] = fmaf(vi, wr, -(vr * wi));
      upk(av.w, vr, vi); upk(bv.w, wr, wi);
      ar[3] = fmaf(vr, wr,  vi * wi); ai[3] = fmaf(vi, wr, -(vr * wi));
    }
    // A1 = (a_r, -a_i) -> C_real ; A2 = (a_i, a_r) -> C_imag
    uint4 au1 = make_uint4(pkbf(ar[0], -ai[0]), pkbf(ar[1], -ai[1]),
                           pkbf(ar[2], -ai[2]), pkbf(ar[3], -ai[3]));
    uint4 au2 = make_uint4(swapvar(au1.x), swapvar(au1.y),
                           swapvar(au1.z), swapvar(au1.w));
    short8 af1 = __builtin_bit_cast(short8, au1);
    short8 af2 = __builtin_bit_cast(short8, au2);
    #pragma unroll
    for (int n = 0; n < 3; n++) {
      short8 bfrag = __builtin_bit_cast(short8, cb[n]);
      acc[n]     = __builtin_amdgcn_mfma_f32_16x16x32_bf16(af1, bfrag, acc[n],     0, 0, 0);
      acc[n + 3] = __builtin_amdgcn_mfma_f32_16x16x32_bf16(af2, bfrag, acc[n + 3], 0, 0, 0);
    }
  }

  // epilogue B-frags + dsinv (no vsh dependency — issue before barrier)
  const uint4* EF = ((const uint4*)((const char*)ws + 197632)) + (mt * 4) * 64 + lane;
  uint4 eb[4];
  #pragma unroll
  for (int ks = 0; ks < 4; ks++) eb[ks] = EF[ks * 64];
  if (tid < 48) dssh[tid] = (tid < NBAND_) ? ws[tid] : 0.f;

  // ---- epilogue GEMM: pv[k][p] = Re(sum_c c2p[p][c]*bc[k][c]) ----
  __syncthreads();                    // all vsh reads done; overlay bcsh
  unsigned* bcsh = smem;              // [48][68] bf16-pair
  #pragma unroll
  for (int n = 0; n < 3; n++) {
    uint4 w4 = make_uint4(pkbf(acc[n][0], acc[n + 3][0]),
                          pkbf(acc[n][1], acc[n + 3][1]),
                          pkbf(acc[n][2], acc[n + 3][2]),
                          pkbf(acc[n][3], acc[n + 3][3]));
    *(uint4*)(bcsh + (n * 16 + m16) * 68 + mt * 16 + quad * 4) = w4;
  }
  __syncthreads();

  float4v eacc[3];
  #pragma unroll
  for (int kt = 0; kt < 3; kt++) eacc[kt] = (float4v){0.f, 0.f, 0.f, 0.f};
  #pragma unroll
  for (int ks = 0; ks < 4; ks++) {
    short8 bfr = __builtin_bit_cast(short8, eb[ks]);
    #pragma unroll
    for (int kt = 0; kt < 3; kt++) {
      uint4 a4 = *(const uint4*)(bcsh + (kt * 16 + m16) * 68 + ks * 16 + quad * 4);
      short8 afr = __builtin_bit_cast(short8, a4);
      eacc[kt] = __builtin_amdgcn_mfma_f32_16x16x32_bf16(afr, bfr, eacc[kt], 0, 0, 0);
    }
  }
  float* op = out + (size_t)bt * (NBAND_ * NPV_);
  #pragma unroll
  for (int kt = 0; kt < 3; kt++) {
    #pragma unroll
    for (int r = 0; r < 4; r++) {
      int k = kt * 16 + quad * 4 + r;
      if (k < NBAND_)
        op[k * 64 + mt * 16 + m16] = eacc[kt][r] * dssh[k];
    }
  }
}

// ---------------- IIR: chunked scan, 320 blocks x 256 thr, chunk=25 ----------------
__global__ __launch_bounds__(256) void pv_iir3(float* __restrict__ z,
                                               const float* __restrict__ tau)
{
  __shared__ float gsh[16][16];
  const int pg = blockIdx.x & 3;
  const int bk = blockIdx.x >> 2;
  const int k = bk % NBAND_;
  const int b = bk / NBAND_;
  const float a  = tau[k];
  const float om = 1.0f - a;
  const int c  = threadIdx.x >> 4;
  const int pl = threadIdx.x & 15;
  const int p  = pg * 16 + pl;
  const size_t stride = (size_t)NBAND_ * 64;
  size_t idx0 = (size_t)b * (T_ * NBAND_ * 64) + (size_t)(c * 25) * stride + k * 64 + p;

  float y[25];
  float accv = 0.f;
  #pragma unroll
  for (int i = 0; i < 25; i++) {
    float v = z[idx0 + (size_t)i * stride];
    accv = fmaf(a, accv, om * v);
    y[i] = accv;
  }
  gsh[c][pl] = accv;
  __syncthreads();
  float a2 = a * a, a8 = a2 * a2 * a2 * a2, a16 = a8 * a8;
  float A = a16 * a8 * a;                   // a^25
  float H = 0.f;
  #pragma unroll
  for (int d = 0; d < 15; d++) {
    if (d < c) H = fmaf(A, H, gsh[d][pl]);
  }
  float wp = a;
  #pragma unroll
  for (int i = 0; i < 25; i++) {
    z[idx0 + (size_t)i * stride] = fmaf(wp, H, y[i]);
    wp *= a;
  }
}

extern "C" void kernel_launch(void* const* d_in, const int* in_sizes, int n_in,
                              void* d_out, int out_size, void* d_ws, size_t ws_size,
                              hipStream_t stream)
{
  const float* br   = (const float*)d_in[0];
  const float* bi   = (const float*)d_in[1];
  const float* bmr  = (const float*)d_in[2];
  const float* bmi  = (const float*)d_in[3];
  const float* c2pr = (const float*)d_in[4];
  const float* c2pi = (const float*)d_in[5];
  const float* tau  = (const float*)d_in[6];
  float* out = (float*)d_out;
  float* ws  = (float*)d_ws;

  hipLaunchKernelGGL(pv_prep, dim3(29), dim3(256), 0, stream,
                     bmr, bmi, c2pr, c2pi, ws);
  hipLaunchKernelGGL(pv_main, dim3(B_ * T_), dim3(256), 0, stream,
                     br, bi, ws, out);
  hipLaunchKernelGGL(pv_iir3, dim3(B_ * NBAND_ * 4), dim3(256), 0, stream,
                     out, tau);
}